// Round 2
// baseline (556.815 us; speedup 1.0000x reference)
//
#include <hip/hip_runtime.h>
#include <hip/hip_bf16.h>

using bf16 = __hip_bfloat16;
using floatx4 = __attribute__((ext_vector_type(4))) float;
using bf16x8  = __attribute__((ext_vector_type(8))) __bf16;

#define MDIM 8192   // B*T
#define NDIM 2048   // C
#define KDIM 2048   // C
#define TSEQ 2048   // T
#define BB   4      // batch
#define CDIM 2048   // C
#define NCHUNK 16
#define TCHUNK 128  // TSEQ/NCHUNK

typedef __attribute__((address_space(1))) void gvoid_t;
typedef __attribute__((address_space(3))) void lvoid_t;

__device__ __forceinline__ void load_lds16(const void* g, void* l) {
  __builtin_amdgcn_global_load_lds((gvoid_t*)(void*)g, (lvoid_t*)l, 16, 0, 0);
}

// ---------------- fp32 -> bf16 convert (grid-stride, 8 elems/thread) ----------
__global__ __launch_bounds__(256) void cvt_f32_bf16(const float* __restrict__ s,
                                                    __bf16* __restrict__ d, int n) {
  int i = (blockIdx.x * 256 + threadIdx.x) * 8;
  const int stride = gridDim.x * 256 * 8;
  for (; i < n; i += stride) {
    float4 a = *(const float4*)(s + i);
    float4 b = *(const float4*)(s + i + 4);
    bf16x8 o;
    o[0] = (__bf16)a.x; o[1] = (__bf16)a.y; o[2] = (__bf16)a.z; o[3] = (__bf16)a.w;
    o[4] = (__bf16)b.x; o[5] = (__bf16)b.y; o[6] = (__bf16)b.z; o[7] = (__bf16)b.w;
    *(bf16x8*)(d + i) = o;
  }
}

// ---------------- GEMM: C[m,n] = sum_k A[m,k] * B[n,k], bf16 in, fp32 acc -----
// 128x128 tile, BK=32, 256 threads = 4 waves in 2x2, each wave 4x4 MFMA 16x16x32.
template <typename CT>
__device__ __forceinline__ void gemm_body(const __bf16* __restrict__ A,
                                          const __bf16* __restrict__ B,
                                          CT* __restrict__ C) {
  __shared__ __bf16 sA[128 * 32];
  __shared__ __bf16 sB[128 * 32];
  const int tid  = threadIdx.x;
  const int lane = tid & 63;
  const int wave = tid >> 6;
  const int wm = (wave >> 1) * 64;
  const int wn = (wave & 1) * 64;
  const int bm = blockIdx.x, bn = blockIdx.y;

  floatx4 acc[4][4] = {};

  const int arow = tid >> 2;          // 0..63
  const int acol = (tid & 3) * 8;     // 0,8,16,24
  const __bf16* Ag = A + (size_t)(bm * 128 + arow) * KDIM + acol;
  const __bf16* Bg = B + (size_t)(bn * 128 + arow) * KDIM + acol;
  __bf16* sAp = sA + tid * 8;         // lane-contiguous: matches lds wave-uniform-base rule
  __bf16* sBp = sB + tid * 8;
  const int fr = lane & 15;           // fragment row (m or n)
  const int fk = (lane >> 4) * 8;     // fragment k offset

  for (int kt = 0; kt < KDIM; kt += 32) {
    load_lds16(Ag,                      sAp);
    load_lds16(Ag + (size_t)64 * KDIM,  sAp + 64 * 32);
    load_lds16(Bg,                      sBp);
    load_lds16(Bg + (size_t)64 * KDIM,  sBp + 64 * 32);
    Ag += 32; Bg += 32;
    __syncthreads();   // drains vmcnt -> LDS visible

    bf16x8 af[4], bfr[4];
#pragma unroll
    for (int i = 0; i < 4; ++i)
      af[i] = *(const bf16x8*)(sA + (wm + i * 16 + fr) * 32 + fk);
#pragma unroll
    for (int j = 0; j < 4; ++j)
      bfr[j] = *(const bf16x8*)(sB + (wn + j * 16 + fr) * 32 + fk);
#pragma unroll
    for (int i = 0; i < 4; ++i)
#pragma unroll
      for (int j = 0; j < 4; ++j)
        acc[i][j] = __builtin_amdgcn_mfma_f32_16x16x32_bf16(af[i], bfr[j], acc[i][j], 0, 0, 0);
    __syncthreads();   // protect LDS before next stage
  }

  // C/D layout: col = lane&15, row = (lane>>4)*4 + reg
  const int crow = (lane >> 4) * 4;
  const int ccol = lane & 15;
#pragma unroll
  for (int i = 0; i < 4; ++i)
#pragma unroll
    for (int j = 0; j < 4; ++j) {
      const size_t r0 = (size_t)(bm * 128 + wm + i * 16 + crow);
      const int    c0 = bn * 128 + wn + j * 16 + ccol;
#pragma unroll
      for (int rg = 0; rg < 4; ++rg)
        C[(r0 + rg) * NDIM + c0] = (CT)(acc[i][j][rg]);
    }
}

__global__ __launch_bounds__(256) void gemm_qkv(const __bf16* __restrict__ x,
                                                const __bf16* __restrict__ Wk,
                                                const __bf16* __restrict__ Wv,
                                                const __bf16* __restrict__ Wr,
                                                __bf16* __restrict__ kb,
                                                __bf16* __restrict__ vb,
                                                __bf16* __restrict__ rb) {
  const __bf16* Bsel = (blockIdx.z == 0) ? Wk : (blockIdx.z == 1) ? Wv : Wr;
  __bf16*       Csel = (blockIdx.z == 0) ? kb : (blockIdx.z == 1) ? vb : rb;
  gemm_body<__bf16>(x, Bsel, Csel);
}

__global__ __launch_bounds__(256) void gemm_o(const __bf16* __restrict__ A,
                                              const __bf16* __restrict__ B,
                                              float* __restrict__ C) {
  gemm_body<float>(A, B, C);
}

// ---------------- WKV blocked scan --------------------------------------------
// Phase 1: per (b, chunk, c) compute chunk summary (num,den) from zero state.
__global__ __launch_bounds__(256) void wkv_summary(
    const __bf16* __restrict__ kb, const __bf16* __restrict__ vb,
    const float* __restrict__ td, const float* __restrict__ tf,
    float* __restrict__ nsum, float* __restrict__ dsum) {
  const int c = blockIdx.x * 256 + threadIdx.x;  // channel = h*128+s
  const int chunk = blockIdx.y;
  const int b = blockIdx.z;
  const float ed = __expf(td[c]);
  const float decay = __expf(-ed);
  const float first = __expf(tf[c]);
  size_t base = ((size_t)b * TSEQ + (size_t)chunk * TCHUNK) * CDIM + c;
  float num = 0.f, den = 0.f;
#pragma unroll 4
  for (int t = 0; t < TCHUNK; ++t) {
    float kk = (float)kb[base + (size_t)t * CDIM];
    float vv = (float)vb[base + (size_t)t * CDIM];
    kk = fminf(fmaxf(kk, -10.f), 10.f);
    float w = __expf(kk);
    if (chunk == 0 && t == 0) w *= first;
    num = decay * num + w * vv;
    den = decay * den + w;
  }
  const int si = (chunk * BB + b) * CDIM + c;
  nsum[si] = num;
  dsum[si] = den;
}

// Phase 2: combine prefixes (redundant per chunk, cheap) + replay chunk,
// fuse sigmoid(r)*wkv. Writes bf16 rwkv in-place over rb.
__global__ __launch_bounds__(256) void wkv_apply(
    const __bf16* __restrict__ kb, const __bf16* __restrict__ vb,
    __bf16* __restrict__ rb,
    const float* __restrict__ td, const float* __restrict__ tf,
    const float* __restrict__ nsum, const float* __restrict__ dsum) {
  const int c = blockIdx.x * 256 + threadIdx.x;
  const int chunk = blockIdx.y;
  const int b = blockIdx.z;
  const float ed = __expf(td[c]);
  const float decay = __expf(-ed);
  const float dTC = __expf(-ed * (float)TCHUNK);  // decay^TCHUNK
  const float first = __expf(tf[c]);

  float num = 0.f, den = 0.f;
  for (int j = 0; j < chunk; ++j) {
    const int si = (j * BB + b) * CDIM + c;
    num = dTC * num + nsum[si];
    den = dTC * den + dsum[si];
  }
  size_t base = ((size_t)b * TSEQ + (size_t)chunk * TCHUNK) * CDIM + c;
#pragma unroll 2
  for (int t = 0; t < TCHUNK; ++t) {
    const size_t idx = base + (size_t)t * CDIM;
    float kk = (float)kb[idx];
    float vv = (float)vb[idx];
    kk = fminf(fmaxf(kk, -10.f), 10.f);
    float w = __expf(kk);
    if (chunk == 0 && t == 0) w *= first;
    num = decay * num + w * vv;
    den = decay * den + w;
    const float wkv = num / (den + 1e-6f);
    const float r = (float)rb[idx];
    const float sr = 1.f / (1.f + __expf(-r));
    rb[idx] = (__bf16)(sr * wkv);
  }
}

// ---------------- launch -------------------------------------------------------
extern "C" void kernel_launch(void* const* d_in, const int* in_sizes, int n_in,
                              void* d_out, int out_size, void* d_ws, size_t ws_size,
                              hipStream_t stream) {
  const float* x  = (const float*)d_in[0];
  const float* Wk = (const float*)d_in[1];
  const float* Wv = (const float*)d_in[2];
  const float* Wr = (const float*)d_in[3];
  const float* Wo = (const float*)d_in[4];
  const float* td = (const float*)d_in[5];
  const float* tf = (const float*)d_in[6];
  float* out = (float*)d_out;

  char* ws = (char*)d_ws;
  const size_t matX = (size_t)MDIM * KDIM * sizeof(__bf16);  // 33.5 MB
  const size_t matW = (size_t)NDIM * KDIM * sizeof(__bf16);  // 8.4 MB
  __bf16* xb  = (__bf16*)(ws);
  __bf16* wkb = (__bf16*)(ws + matX);
  __bf16* wvb = (__bf16*)(ws + matX + matW);
  __bf16* wrb = (__bf16*)(ws + matX + 2 * matW);
  __bf16* wob = (__bf16*)(ws + matX + 3 * matW);
  __bf16* kb  = (__bf16*)(ws + matX + 4 * matW);
  __bf16* vb  = (__bf16*)(ws + 2 * matX + 4 * matW);
  __bf16* rb  = (__bf16*)(ws + 3 * matX + 4 * matW);
  float* nsum = (float*)(ws + 4 * matX + 4 * matW);
  float* dsum = nsum + NCHUNK * BB * CDIM;
  // total ws use: 4*33.5MB + 4*8.4MB + 1MB ~= 169 MB

  dim3 blk(256);
  const int nx = MDIM * KDIM, nw = NDIM * KDIM;
  cvt_f32_bf16<<<dim3(nx / (8 * 256)), blk, 0, stream>>>(x,  xb,  nx);
  cvt_f32_bf16<<<dim3(nw / (8 * 256)), blk, 0, stream>>>(Wk, wkb, nw);
  cvt_f32_bf16<<<dim3(nw / (8 * 256)), blk, 0, stream>>>(Wv, wvb, nw);
  cvt_f32_bf16<<<dim3(nw / (8 * 256)), blk, 0, stream>>>(Wr, wrb, nw);
  cvt_f32_bf16<<<dim3(nw / (8 * 256)), blk, 0, stream>>>(Wo, wob, nw);

  dim3 gq(MDIM / 128, NDIM / 128, 3);
  gemm_qkv<<<gq, blk, 0, stream>>>(xb, wkb, wvb, wrb, kb, vb, rb);
  dim3 gw(CDIM / 256, NCHUNK, BB);
  wkv_summary<<<gw, blk, 0, stream>>>(kb, vb, td, tf, nsum, dsum);
  wkv_apply<<<gw, blk, 0, stream>>>(kb, vb, rb, td, tf, nsum, dsum);
  dim3 go(MDIM / 128, NDIM / 128, 1);
  gemm_o<<<go, blk, 0, stream>>>(rb, wob, out);
}

// Round 3
// 539.121 us; speedup vs baseline: 1.0328x; 1.0328x over previous
//
#include <hip/hip_runtime.h>
#include <hip/hip_bf16.h>

using bf16 = __hip_bfloat16;
using floatx4 = __attribute__((ext_vector_type(4))) float;
using bf16x8  = __attribute__((ext_vector_type(8))) __bf16;
using bf16x2  = __attribute__((ext_vector_type(2))) __bf16;

#define MDIM 8192   // B*T
#define NDIM 2048   // C
#define KDIM 2048   // C
#define TSEQ 2048   // T
#define BB   4      // batch
#define CDIM 2048   // C
#define NCHUNK 32
#define TCHUNK 64   // TSEQ/NCHUNK

typedef __attribute__((address_space(1))) void gvoid_t;
typedef __attribute__((address_space(3))) void lvoid_t;

__device__ __forceinline__ void load_lds16(const void* g, void* l) {
  __builtin_amdgcn_global_load_lds((gvoid_t*)(void*)g, (lvoid_t*)l, 16, 0, 0);
}

// ---------------- fp32 -> bf16 converts ---------------------------------------
__global__ __launch_bounds__(256) void cvt_x(const float* __restrict__ s,
                                             __bf16* __restrict__ d) {
  const int i = (blockIdx.x * 256 + threadIdx.x) * 8;
  float4 a = *(const float4*)(s + i);
  float4 b = *(const float4*)(s + i + 4);
  bf16x8 o;
  o[0] = (__bf16)a.x; o[1] = (__bf16)a.y; o[2] = (__bf16)a.z; o[3] = (__bf16)a.w;
  o[4] = (__bf16)b.x; o[5] = (__bf16)b.y; o[6] = (__bf16)b.z; o[7] = (__bf16)b.w;
  *(bf16x8*)(d + i) = o;
}

// 4 weight matrices, one per gridDim.y slice
__global__ __launch_bounds__(256) void cvt_w(const float* __restrict__ s0,
                                             const float* __restrict__ s1,
                                             const float* __restrict__ s2,
                                             const float* __restrict__ s3,
                                             __bf16* __restrict__ d0,
                                             __bf16* __restrict__ d1,
                                             __bf16* __restrict__ d2,
                                             __bf16* __restrict__ d3) {
  const float* s = (blockIdx.y == 0) ? s0 : (blockIdx.y == 1) ? s1
                 : (blockIdx.y == 2) ? s2 : s3;
  __bf16*      d = (blockIdx.y == 0) ? d0 : (blockIdx.y == 1) ? d1
                 : (blockIdx.y == 2) ? d2 : d3;
  const int i = (blockIdx.x * 256 + threadIdx.x) * 8;
  float4 a = *(const float4*)(s + i);
  float4 b = *(const float4*)(s + i + 4);
  bf16x8 o;
  o[0] = (__bf16)a.x; o[1] = (__bf16)a.y; o[2] = (__bf16)a.z; o[3] = (__bf16)a.w;
  o[4] = (__bf16)b.x; o[5] = (__bf16)b.y; o[6] = (__bf16)b.z; o[7] = (__bf16)b.w;
  *(bf16x8*)(d + i) = o;
}

// ---------------- GEMM: C[m,n] = sum_k A[m,k] * B[n,k], bf16 in, fp32 acc -----
// 128x128 tile, BK=32, 256 threads = 4 waves in 2x2, each wave 4x4 MFMA 16x16x32.
template <typename CT>
__device__ __forceinline__ void gemm_body(const __bf16* __restrict__ A,
                                          const __bf16* __restrict__ B,
                                          CT* __restrict__ C) {
  __shared__ __bf16 sA[128 * 32];
  __shared__ __bf16 sB[128 * 32];
  const int tid  = threadIdx.x;
  const int lane = tid & 63;
  const int wave = tid >> 6;
  const int wm = (wave >> 1) * 64;
  const int wn = (wave & 1) * 64;
  const int bm = blockIdx.x, bn = blockIdx.y;

  floatx4 acc[4][4] = {};

  const int arow = tid >> 2;          // 0..63
  const int acol = (tid & 3) * 8;     // 0,8,16,24
  const __bf16* Ag = A + (size_t)(bm * 128 + arow) * KDIM + acol;
  const __bf16* Bg = B + (size_t)(bn * 128 + arow) * KDIM + acol;
  __bf16* sAp = sA + tid * 8;         // lane-contiguous (global_load_lds rule)
  __bf16* sBp = sB + tid * 8;
  const int fr = lane & 15;           // fragment row (m or n)
  const int fk = (lane >> 4) * 8;     // fragment k offset

  for (int kt = 0; kt < KDIM; kt += 32) {
    load_lds16(Ag,                      sAp);
    load_lds16(Ag + (size_t)64 * KDIM,  sAp + 64 * 32);
    load_lds16(Bg,                      sBp);
    load_lds16(Bg + (size_t)64 * KDIM,  sBp + 64 * 32);
    Ag += 32; Bg += 32;
    __syncthreads();

    bf16x8 af[4], bfr[4];
#pragma unroll
    for (int i = 0; i < 4; ++i)
      af[i] = *(const bf16x8*)(sA + (wm + i * 16 + fr) * 32 + fk);
#pragma unroll
    for (int j = 0; j < 4; ++j)
      bfr[j] = *(const bf16x8*)(sB + (wn + j * 16 + fr) * 32 + fk);
#pragma unroll
    for (int i = 0; i < 4; ++i)
#pragma unroll
      for (int j = 0; j < 4; ++j)
        acc[i][j] = __builtin_amdgcn_mfma_f32_16x16x32_bf16(af[i], bfr[j], acc[i][j], 0, 0, 0);
    __syncthreads();
  }

  // C/D layout: col = lane&15, row = (lane>>4)*4 + reg
  const int crow = (lane >> 4) * 4;
  const int ccol = lane & 15;
#pragma unroll
  for (int i = 0; i < 4; ++i)
#pragma unroll
    for (int j = 0; j < 4; ++j) {
      const size_t r0 = (size_t)(bm * 128 + wm + i * 16 + crow);
      const int    c0 = bn * 128 + wn + j * 16 + ccol;
#pragma unroll
      for (int rg = 0; rg < 4; ++rg)
        C[(r0 + rg) * NDIM + c0] = (CT)(acc[i][j][rg]);
    }
}

__global__ __launch_bounds__(256) void gemm_qkv(const __bf16* __restrict__ x,
                                                const __bf16* __restrict__ Wk,
                                                const __bf16* __restrict__ Wv,
                                                const __bf16* __restrict__ Wr,
                                                __bf16* __restrict__ kb,
                                                __bf16* __restrict__ vb,
                                                __bf16* __restrict__ rb) {
  const __bf16* Bsel = (blockIdx.z == 0) ? Wk : (blockIdx.z == 1) ? Wv : Wr;
  __bf16*       Csel = (blockIdx.z == 0) ? kb : (blockIdx.z == 1) ? vb : rb;
  gemm_body<__bf16>(x, Bsel, Csel);
}

__global__ __launch_bounds__(256) void gemm_o(const __bf16* __restrict__ A,
                                              const __bf16* __restrict__ B,
                                              float* __restrict__ C) {
  gemm_body<float>(A, B, C);
}

// ---------------- WKV blocked scan: 2 channels/thread --------------------------
// Phase 1: per (b, chunk, c-pair) chunk summary (num,den) from zero state.
__global__ __launch_bounds__(256) void wkv_summary(
    const __bf16* __restrict__ kb, const __bf16* __restrict__ vb,
    const float* __restrict__ td, const float* __restrict__ tf,
    float* __restrict__ nsum, float* __restrict__ dsum) {
  const int c0 = (blockIdx.x * 256 + threadIdx.x) * 2;
  const int chunk = blockIdx.y;
  const int b = blockIdx.z;
  const float dc0 = __expf(-__expf(td[c0]));
  const float dc1 = __expf(-__expf(td[c0 + 1]));
  const float fi0 = __expf(tf[c0]);
  const float fi1 = __expf(tf[c0 + 1]);
  size_t base = ((size_t)b * TSEQ + (size_t)chunk * TCHUNK) * CDIM + c0;
  float n0 = 0.f, d0 = 0.f, n1 = 0.f, d1 = 0.f;
#pragma unroll 4
  for (int t = 0; t < TCHUNK; ++t) {
    bf16x2 k2 = *(const bf16x2*)(kb + base + (size_t)t * CDIM);
    bf16x2 v2 = *(const bf16x2*)(vb + base + (size_t)t * CDIM);
    float k0f = fminf(fmaxf((float)k2[0], -10.f), 10.f);
    float k1f = fminf(fmaxf((float)k2[1], -10.f), 10.f);
    float w0 = __expf(k0f), w1 = __expf(k1f);
    if (chunk == 0 && t == 0) { w0 *= fi0; w1 *= fi1; }
    n0 = dc0 * n0 + w0 * (float)v2[0];
    d0 = dc0 * d0 + w0;
    n1 = dc1 * n1 + w1 * (float)v2[1];
    d1 = dc1 * d1 + w1;
  }
  const size_t si = (size_t)(chunk * BB + b) * CDIM + c0;
  *(float2*)(nsum + si) = make_float2(n0, n1);
  *(float2*)(dsum + si) = make_float2(d0, d1);
}

// Phase 2: redundant prefix combine + chunk replay, fuse sigmoid(r)*wkv in-place.
__global__ __launch_bounds__(256) void wkv_apply(
    const __bf16* __restrict__ kb, const __bf16* __restrict__ vb,
    __bf16* __restrict__ rb,
    const float* __restrict__ td, const float* __restrict__ tf,
    const float* __restrict__ nsum, const float* __restrict__ dsum) {
  const int c0 = (blockIdx.x * 256 + threadIdx.x) * 2;
  const int chunk = blockIdx.y;
  const int b = blockIdx.z;
  const float ed0 = __expf(td[c0]);
  const float ed1 = __expf(td[c0 + 1]);
  const float dc0 = __expf(-ed0);
  const float dc1 = __expf(-ed1);
  const float dT0 = __expf(-ed0 * (float)TCHUNK);  // decay^TCHUNK
  const float dT1 = __expf(-ed1 * (float)TCHUNK);
  const float fi0 = __expf(tf[c0]);
  const float fi1 = __expf(tf[c0 + 1]);

  float n0 = 0.f, d0 = 0.f, n1 = 0.f, d1 = 0.f;
  for (int j = 0; j < chunk; ++j) {
    const size_t si = (size_t)(j * BB + b) * CDIM + c0;
    float2 ns = *(const float2*)(nsum + si);
    float2 ds = *(const float2*)(dsum + si);
    n0 = dT0 * n0 + ns.x;  d0 = dT0 * d0 + ds.x;
    n1 = dT1 * n1 + ns.y;  d1 = dT1 * d1 + ds.y;
  }
  size_t base = ((size_t)b * TSEQ + (size_t)chunk * TCHUNK) * CDIM + c0;
#pragma unroll 2
  for (int t = 0; t < TCHUNK; ++t) {
    const size_t idx = base + (size_t)t * CDIM;
    bf16x2 k2 = *(const bf16x2*)(kb + idx);
    bf16x2 v2 = *(const bf16x2*)(vb + idx);
    bf16x2 r2 = *(const bf16x2*)(rb + idx);
    float k0f = fminf(fmaxf((float)k2[0], -10.f), 10.f);
    float k1f = fminf(fmaxf((float)k2[1], -10.f), 10.f);
    float w0 = __expf(k0f), w1 = __expf(k1f);
    if (chunk == 0 && t == 0) { w0 *= fi0; w1 *= fi1; }
    n0 = dc0 * n0 + w0 * (float)v2[0];
    d0 = dc0 * d0 + w0;
    n1 = dc1 * n1 + w1 * (float)v2[1];
    d1 = dc1 * d1 + w1;
    const float wkv0 = n0 * __builtin_amdgcn_rcpf(d0 + 1e-6f);
    const float wkv1 = n1 * __builtin_amdgcn_rcpf(d1 + 1e-6f);
    const float sr0 = __builtin_amdgcn_rcpf(1.f + __expf(-(float)r2[0]));
    const float sr1 = __builtin_amdgcn_rcpf(1.f + __expf(-(float)r2[1]));
    bf16x2 o;
    o[0] = (__bf16)(sr0 * wkv0);
    o[1] = (__bf16)(sr1 * wkv1);
    *(bf16x2*)(rb + idx) = o;
  }
}

// ---------------- launch -------------------------------------------------------
extern "C" void kernel_launch(void* const* d_in, const int* in_sizes, int n_in,
                              void* d_out, int out_size, void* d_ws, size_t ws_size,
                              hipStream_t stream) {
  const float* x  = (const float*)d_in[0];
  const float* Wk = (const float*)d_in[1];
  const float* Wv = (const float*)d_in[2];
  const float* Wr = (const float*)d_in[3];
  const float* Wo = (const float*)d_in[4];
  const float* td = (const float*)d_in[5];
  const float* tf = (const float*)d_in[6];
  float* out = (float*)d_out;

  char* ws = (char*)d_ws;
  const size_t matX = (size_t)MDIM * KDIM * sizeof(__bf16);  // 33.5 MB
  const size_t matW = (size_t)NDIM * KDIM * sizeof(__bf16);  // 8.4 MB
  __bf16* xb  = (__bf16*)(ws);
  __bf16* wkb = (__bf16*)(ws + matX);
  __bf16* wvb = (__bf16*)(ws + matX + matW);
  __bf16* wrb = (__bf16*)(ws + matX + 2 * matW);
  __bf16* wob = (__bf16*)(ws + matX + 3 * matW);
  __bf16* kb  = (__bf16*)(ws + matX + 4 * matW);
  __bf16* vb  = (__bf16*)(ws + 2 * matX + 4 * matW);
  __bf16* rb  = (__bf16*)(ws + 3 * matX + 4 * matW);
  float* nsum = (float*)(ws + 4 * matX + 4 * matW);
  float* dsum = nsum + (size_t)NCHUNK * BB * CDIM;
  // ws use: 4*33.5MB + 4*8.4MB + 2MB ~= 170 MB

  dim3 blk(256);
  cvt_x<<<dim3(MDIM * KDIM / (8 * 256)), blk, 0, stream>>>(x, xb);
  cvt_w<<<dim3(NDIM * KDIM / (8 * 256), 4), blk, 0, stream>>>(
      Wk, Wv, Wr, Wo, wkb, wvb, wrb, wob);

  dim3 gq(MDIM / 128, NDIM / 128, 3);
  gemm_qkv<<<gq, blk, 0, stream>>>(xb, wkb, wvb, wrb, kb, vb, rb);
  dim3 gw(CDIM / 512, NCHUNK, BB);
  wkv_summary<<<gw, blk, 0, stream>>>(kb, vb, td, tf, nsum, dsum);
  wkv_apply<<<gw, blk, 0, stream>>>(kb, vb, rb, td, tf, nsum, dsum);
  dim3 go(MDIM / 128, NDIM / 128, 1);
  gemm_o<<<go, blk, 0, stream>>>(rb, wob, out);
}